// Round 7
// baseline (2591.033 us; speedup 1.0000x reference)
//
#include <hip/hip_runtime.h>
#include <stdint.h>

// ResRnn persistent kernel. R7:
//  - Ring-buffered state/h (depth D from ws_size) read with NORMAL CACHED loads:
//    8 same-group WGs per XCD share L2 refills (8x fabric cut). Stores remain
//    relaxed agent (sc1) write-through so LLC is always current. One acquire
//    (buffer_inv) per wave every D/2 steps guarantees no stale line can survive
//    the D-step address-reuse distance. Fallback <COH=true>: sc1-direct reads.
//  - Per-ks pipelined waits on per-chunk monotone COUNTERS (4 per-wave relaxed
//    fetch_add signals/chunk, 64B-padded): fixed unroll order (weights stay in
//    regs), compute overlaps straggling producers.
//  - LDS reduce double-buffered -> only 2 __syncthreads/step, which also serve
//    as the intra-WG gates making the cross-WG overwrite races impossible.

#define NSTEPS 128
#define NB 128
#define WID 2048
#define SS 1984

#define SFSZ 1015808   // 128*1984*4
#define SBSZ 507904    // 128*1984*2
#define HSZ  524288    // 128*2048*2

typedef __attribute__((ext_vector_type(8))) short short8;
typedef __attribute__((ext_vector_type(4))) short short4v;
typedef __attribute__((ext_vector_type(4))) float f32x4;
typedef unsigned long long u64;

static __device__ __forceinline__ short f2bf(float f) {
  union { float f; unsigned u; } v; v.f = f;
  unsigned r = (v.u + 0x7fffu + ((v.u >> 16) & 1u)) >> 16;  // RNE
  return (short)r;
}
static __device__ __forceinline__ short8 pack8(f32x4 lo, f32x4 hi) {
  short8 r;
  r[0] = f2bf(lo[0]); r[1] = f2bf(lo[1]); r[2] = f2bf(lo[2]); r[3] = f2bf(lo[3]);
  r[4] = f2bf(hi[0]); r[5] = f2bf(hi[1]); r[6] = f2bf(hi[2]); r[7] = f2bf(hi[3]);
  return r;
}
static __device__ __forceinline__ void ast64(void* p, u64 v) {
  __hip_atomic_store((u64*)p, v, __ATOMIC_RELAXED, __HIP_MEMORY_SCOPE_AGENT);
}
static __device__ __forceinline__ u64 ald64(const void* p) {
  return __hip_atomic_load((const u64*)p, __ATOMIC_RELAXED, __HIP_MEMORY_SCOPE_AGENT);
}
static __device__ __forceinline__ unsigned ald32(const unsigned* p) {
  return __hip_atomic_load(p, __ATOMIC_RELAXED, __HIP_MEMORY_SCOPE_AGENT);
}
static __device__ __forceinline__ short8 ald_s8(const void* p) {
  union { u64 u[2]; short8 s; } r;
  r.u[0] = ald64((const char*)p); r.u[1] = ald64((const char*)p + 8);
  return r.s;
}
static __device__ __forceinline__ f32x4 ald_f4(const void* p) {
  union { u64 u[2]; f32x4 f; } r;
  r.u[0] = ald64((const char*)p); r.u[1] = ald64((const char*)p + 8);
  return r.f;
}

template<bool COH, int D>
__global__ __launch_bounds__(256, 1)
void resrnn_kernel(const float* __restrict__ inp, const float* __restrict__ W1,
                   const float* __restrict__ b1f, const float* __restrict__ W2,
                   const float* __restrict__ b2f, float* __restrict__ out,
                   unsigned char* __restrict__ ws)
{
  const int tid   = threadIdx.x;
  const int bid   = blockIdx.x;
  const int group = bid & 3;
  const int chunk = bid >> 2;
  const int mbase = group * 32;
  const int n0    = chunk * 32;
  const int wave  = tid >> 6;
  const int lane  = tid & 63;
  const int l15   = lane & 15;
  const int q8    = (lane >> 4) * 8;
  const int kb    = wave * 512;

  // per-group counter arrays: 64 chunks x 64B (16 u32 stride). Monotone: +4/step.
  unsigned* scnt = (unsigned*)(ws + group * 8192);
  unsigned* hcnt = (unsigned*)(ws + group * 8192 + 4096);
  unsigned char* base = ws + 32768;
  float* SfR = (float*)base;
  short* SbR = (short*)(base + (size_t)D * SFSZ);
  short* hbR = (short*)(base + (size_t)D * (SFSZ + SBSZ));

  __shared__ float red1[4][16][65];
  __shared__ float red2[4][16][65];

  // ---- one-time: weight B-fragments into registers ----
  short8 B1[16][2], B2[16][2];
#pragma unroll
  for (int ks = 0; ks < 16; ++ks) {
#pragma unroll
    for (int nt = 0; nt < 2; ++nt) {
      const float* p1 = W1 + (size_t)(n0 + nt * 16 + l15) * WID + (kb + ks * 32 + q8);
      B1[ks][nt] = pack8(*(const f32x4*)p1, *(const f32x4*)(p1 + 4));
      const float* p2 = W2 + (size_t)(n0 + nt * 16 + l15) * WID + (kb + ks * 32 + q8);
      B2[ks][nt] = pack8(*(const f32x4*)p2, *(const f32x4*)(p2 + 4));
    }
  }

  const int m0 = mbase + l15;
  const int m1 = mbase + 16 + l15;
  const int o    = tid * 4;
  const int ml   = o >> 5;
  const int nl   = o & 31;
  const int mrow = mbase + ml;
  const f32x4 b1r = *(const f32x4*)(b1f + n0 + nl);
  const f32x4 b2r = *(const f32x4*)(b2f + n0 + nl);

  // poll pointers: lane i<16 watches the counter for its wave's ks=i producer
  const int p1c = 16 * wave + l15 - 2;
  const bool p1v = (lane < 16) && (p1c >= 0);
  const unsigned* p1poll = scnt + (p1v ? p1c : 0) * 16;
  const bool p2v = (lane < 16);
  const unsigned* p2poll = hcnt + (16 * wave + l15) * 16;

#pragma unroll 1
  for (int t = 0; t < NSTEPS; ++t) {
    const int sW = t & (D - 1);
    const int sR = (t - 1) & (D - 1);
    float*       SfNew = SfR + (size_t)sW * (SFSZ / 4);
    const float* SfOld = SfR + (size_t)sR * (SFSZ / 4);
    short*       SbNew = SbR + (size_t)sW * (SBSZ / 2);
    const short* SbOld = SbR + (size_t)sR * (SBSZ / 2);
    short*       hb    = hbR + (size_t)(COH ? 0 : sW) * (HSZ / 2);

    // periodic acquire: invalidates this wave's L1/L2 view; every D/2 steps.
    if (!COH && (t & (D / 2 - 1)) == 0)
      (void)__hip_atomic_load((const unsigned*)(ws + group * 8192),
                              __ATOMIC_ACQUIRE, __HIP_MEMORY_SCOPE_AGENT);

    // ================= phase 1: u = s@W1^T ; h = |u+b1| =================
    const unsigned tgt1 = 4u * (unsigned)t;
    unsigned rdy = (t == 0) ? 0xFFFFu : 0u;
    f32x4 a00{}, a01{}, a10{}, a11{};
#pragma unroll
    for (int ks = 0; ks < 16; ++ks) {
      if (kb == 0 && ks < 2) {
        const float* p0 = inp + ((size_t)t * NB + m0) * 64 + (ks * 32 + q8);
        const float* p1 = inp + ((size_t)t * NB + m1) * 64 + (ks * 32 + q8);
        short8 x0 = pack8(*(const f32x4*)p0, *(const f32x4*)(p0 + 4));
        short8 x1 = pack8(*(const f32x4*)p1, *(const f32x4*)(p1 + 4));
        a00 = __builtin_amdgcn_mfma_f32_16x16x32_bf16(x0, B1[ks][0], a00, 0, 0, 0);
        a01 = __builtin_amdgcn_mfma_f32_16x16x32_bf16(x0, B1[ks][1], a01, 0, 0, 0);
        a10 = __builtin_amdgcn_mfma_f32_16x16x32_bf16(x1, B1[ks][0], a10, 0, 0, 0);
        a11 = __builtin_amdgcn_mfma_f32_16x16x32_bf16(x1, B1[ks][1], a11, 0, 0, 0);
      } else if (t > 0) {
        while (!(rdy & (1u << ks))) {          // wait only for THIS chunk's producer
          unsigned v = p1v ? ald32(p1poll) : 0xFFFFFFFFu;
          rdy = (unsigned)(__ballot(v >= tgt1) & 0xFFFFull);
        }
        const short* q0 = SbOld + (size_t)m0 * SS + (kb + ks * 32 - 64 + q8);
        const short* q1 = SbOld + (size_t)m1 * SS + (kb + ks * 32 - 64 + q8);
        short8 x0 = COH ? ald_s8(q0) : *(const short8*)q0;
        short8 x1 = COH ? ald_s8(q1) : *(const short8*)q1;
        a00 = __builtin_amdgcn_mfma_f32_16x16x32_bf16(x0, B1[ks][0], a00, 0, 0, 0);
        a01 = __builtin_amdgcn_mfma_f32_16x16x32_bf16(x0, B1[ks][1], a01, 0, 0, 0);
        a10 = __builtin_amdgcn_mfma_f32_16x16x32_bf16(x1, B1[ks][0], a10, 0, 0, 0);
        a11 = __builtin_amdgcn_mfma_f32_16x16x32_bf16(x1, B1[ks][1], a11, 0, 0, 0);
      }
    }
#pragma unroll
    for (int r = 0; r < 4; ++r) {
      red1[wave][r][lane]      = a00[r];
      red1[wave][4 + r][lane]  = a01[r];
      red1[wave][8 + r][lane]  = a10[r];
      red1[wave][12 + r][lane] = a11[r];
    }
    __syncthreads();   // also gates h-writes behind the WG-wide union of S-waits
    {
      short4v hv;
#pragma unroll
      for (int j = 0; j < 4; ++j) {
        const int nn   = nl + j;
        const int lidx = ((ml >> 2) & 3) * 16 + (nn & 15);
        const int ridx = (ml >> 4) * 8 + (nn >> 4) * 4 + (ml & 3);
        float s = red1[0][ridx][lidx] + red1[1][ridx][lidx]
                + red1[2][ridx][lidx] + red1[3][ridx][lidx] + b1r[j];
        hv[j] = f2bf(fabsf(s));
      }
      union { short4v s; u64 u; } hu; hu.s = hv;
      ast64(hb + (size_t)mrow * WID + (n0 + nl), hu.u);
    }
    asm volatile("s_waitcnt vmcnt(0)" ::: "memory");   // this wave's h at LLC
    if (lane == 0)
      __hip_atomic_fetch_add(hcnt + chunk * 16, 1u,
                             __ATOMIC_RELAXED, __HIP_MEMORY_SCOPE_AGENT);

    // ================= phase 2: g = h@W2^T ; state update =================
    const unsigned tgt2 = 4u * ((unsigned)t + 1u);
    unsigned rdy2 = 0u;
    f32x4 c00{}, c01{}, c10{}, c11{};
    {
      const short* h0 = hb + (size_t)m0 * WID + kb + q8;
      const short* h1 = hb + (size_t)m1 * WID + kb + q8;
#pragma unroll
      for (int ks = 0; ks < 16; ++ks) {
        while (!(rdy2 & (1u << ks))) {
          unsigned v = p2v ? ald32(p2poll) : 0xFFFFFFFFu;
          rdy2 = (unsigned)(__ballot(v >= tgt2) & 0xFFFFull);
        }
        short8 x0 = COH ? ald_s8(h0 + ks * 32) : *(const short8*)(h0 + ks * 32);
        short8 x1 = COH ? ald_s8(h1 + ks * 32) : *(const short8*)(h1 + ks * 32);
        c00 = __builtin_amdgcn_mfma_f32_16x16x32_bf16(x0, B2[ks][0], c00, 0, 0, 0);
        c01 = __builtin_amdgcn_mfma_f32_16x16x32_bf16(x0, B2[ks][1], c01, 0, 0, 0);
        c10 = __builtin_amdgcn_mfma_f32_16x16x32_bf16(x1, B2[ks][0], c10, 0, 0, 0);
        c11 = __builtin_amdgcn_mfma_f32_16x16x32_bf16(x1, B2[ks][1], c11, 0, 0, 0);
      }
    }
#pragma unroll
    for (int r = 0; r < 4; ++r) {
      red2[wave][r][lane]      = c00[r];
      red2[wave][4 + r][lane]  = c01[r];
      red2[wave][8 + r][lane]  = c10[r];
      red2[wave][12 + r][lane] = c11[r];
    }
    __syncthreads();   // also gates S-writes behind the WG-wide union of h-waits
    if (t < NSTEPS - 1) {
      if (n0 < SS) {
        f32x4 gv;
#pragma unroll
        for (int j = 0; j < 4; ++j) {
          const int nn   = nl + j;
          const int lidx = ((ml >> 2) & 3) * 16 + (nn & 15);
          const int ridx = (ml >> 4) * 8 + (nn >> 4) * 4 + (ml & 3);
          gv[j] = red2[0][ridx][lidx] + red2[1][ridx][lidx]
                + red2[2][ridx][lidx] + red2[3][ridx][lidx] + b2r[j];
        }
        const int c0 = n0 + nl;
        f32x4 prev;
        if (c0 < 64) {
          prev = *(const f32x4*)(inp + ((size_t)t * NB + mrow) * 64 + c0);
        } else if (t > 0) {   // covered by this WG's phase-1 waits (chunk c-2 <= 61)
          const float* pp = SfOld + (size_t)mrow * SS + (c0 - 64);
          prev = COH ? ald_f4(pp) : *(const f32x4*)pp;
        } else {
          prev = f32x4{0.f, 0.f, 0.f, 0.f};
        }
        f32x4 sv; short4v sb;
#pragma unroll
        for (int j = 0; j < 4; ++j) {
          float vv = 0.9f * prev[j] + 0.1f * gv[j];
          sv[j] = vv; sb[j] = f2bf(vv);
        }
        union { f32x4 f; u64 u[2]; } sfu; sfu.f = sv;
        float* pf = SfNew + (size_t)mrow * SS + c0;
        ast64(pf, sfu.u[0]);
        ast64(pf + 2, sfu.u[1]);
        union { short4v s; u64 u; } sbu; sbu.s = sb;
        ast64(SbNew + (size_t)mrow * SS + c0, sbu.u);
      }
      asm volatile("s_waitcnt vmcnt(0)" ::: "memory");
      if (lane == 0 && chunk < 62)
        __hip_atomic_fetch_add(scnt + chunk * 16, 1u,
                               __ATOMIC_RELAXED, __HIP_MEMORY_SCOPE_AGENT);
    } else {
      if (n0 >= SS) {
        f32x4 gv;
#pragma unroll
        for (int j = 0; j < 4; ++j) {
          const int nn   = nl + j;
          const int lidx = ((ml >> 2) & 3) * 16 + (nn & 15);
          const int ridx = (ml >> 4) * 8 + (nn >> 4) * 4 + (ml & 3);
          gv[j] = red2[0][ridx][lidx] + red2[1][ridx][lidx]
                + red2[2][ridx][lidx] + red2[3][ridx][lidx] + b2r[j];
        }
        const int c0 = n0 + nl;
        const float* pp = SfOld + (size_t)mrow * SS + (c0 - 64);
        f32x4 prev = COH ? ald_f4(pp) : *(const f32x4*)pp;
        f32x4 ov;
#pragma unroll
        for (int j = 0; j < 4; ++j) ov[j] = 0.9f * prev[j] + 0.1f * gv[j];
        *(f32x4*)(out + (size_t)mrow * 64 + (c0 - SS)) = ov;
      }
    }
  }
}

extern "C" void kernel_launch(void* const* d_in, const int* in_sizes, int n_in,
                              void* d_out, int out_size, void* d_ws, size_t ws_size,
                              hipStream_t stream)
{
  (void)in_sizes; (void)n_in; (void)out_size;
  const float* inp = (const float*)d_in[0];
  const float* W1  = (const float*)d_in[1];
  const float* b1  = (const float*)d_in[2];
  const float* W2  = (const float*)d_in[3];
  const float* b2  = (const float*)d_in[4];
  float* out = (float*)d_out;
  unsigned char* ws = (unsigned char*)d_ws;

  hipMemsetAsync(d_ws, 0, 32768, stream);  // counters

  const size_t slot = (size_t)SFSZ + SBSZ + HSZ;  // 2048000 B per ring slot
  auto fits = [&](int d) { return 32768 + (size_t)d * slot <= ws_size; };
  dim3 g(256), b(256);
  if (fits(16))
    resrnn_kernel<false, 16><<<g, b, 0, stream>>>(inp, W1, b1, W2, b2, out, ws);
  else if (fits(8))
    resrnn_kernel<false, 8><<<g, b, 0, stream>>>(inp, W1, b1, W2, b2, out, ws);
  else if (fits(4))
    resrnn_kernel<false, 4><<<g, b, 0, stream>>>(inp, W1, b1, W2, b2, out, ws);
  else if (fits(2))
    resrnn_kernel<false, 2><<<g, b, 0, stream>>>(inp, W1, b1, W2, b2, out, ws);
  else  // compact fallback (h single-slot): sc1-direct reads, ~3.6 MB
    resrnn_kernel<true, 2><<<g, b, 0, stream>>>(inp, W1, b1, W2, b2, out, ws);
}